// Round 3
// baseline (229.838 us; speedup 1.0000x reference)
//
#include <hip/hip_runtime.h>
#include <math.h>

#define NN 384
#define NSQ (NN*NN)          // 147456

// workspace float offsets
#define WS_MASKF 0           // 384
#define WS_C1    384         // 384*8   = 3072
#define WS_P     3456        // 384*512 = 196608
#define WS_VN    200064      // 384*256 = 98304
#define WS_T     298368      // 384*512 = 196608
#define WS_GH    494976      // 64*384  = 24576
// total 519552 floats = ~2.08 MB

// ---------------------------------------------------------------------------
// K1: q/kn/vn projections + c1[h,i] = sum_a q*kn, P[h,c,i] = sum_a q*Wk_edge.
// Blocks 0..47: one block handles 8 columns i. Block 48: mask normalize.
__global__ __launch_bounds__(256) void k_proj(
    const float* __restrict__ nodes, const float* __restrict__ Wq,
    const float* __restrict__ Wk, const float* __restrict__ Wv,
    const unsigned int* __restrict__ mi, float* __restrict__ ws) {
    int tid = threadIdx.x;
    if (blockIdx.x == 48) {
        // mask -> float {0,1}; detect int32 vs packed-byte delivery.
        __shared__ int bytemode;
        if (tid == 0) bytemode = 0;
        __syncthreads();
        unsigned v0 = mi[tid];
        unsigned v1 = (tid < 128) ? mi[256 + tid] : 0u;
        if (v0 > 1u || v1 > 1u) bytemode = 1;   // benign race
        __syncthreads();
        float* maskf = ws + WS_MASKF;
        for (int j = tid; j < NN; j += 256) {
            int on;
            if (bytemode) on = (((const unsigned char*)mi)[j] != 0);
            else          on = (mi[j] != 0u);
            maskf[j] = on ? 1.0f : 0.0f;
        }
        return;
    }
    float* c1_ws = ws + WS_C1;
    float* P_ws  = ws + WS_P;
    float* vn_ws = ws + WS_VN;
    int i0 = blockIdx.x * 8;
    __shared__ float nl[128][8];
    __shared__ float q_l[256][8];
    __shared__ float qk_l[256][8];
    for (int idx = tid; idx < 1024; idx += 256) {
        int m = idx >> 3, ii = idx & 7;
        nl[m][ii] = nodes[m * NN + i0 + ii];
    }
    __syncthreads();
    int o = tid;
    float aq[8], ak[8], av[8];
#pragma unroll
    for (int ii = 0; ii < 8; ii++) { aq[ii] = 0.f; ak[ii] = 0.f; av[ii] = 0.f; }
#pragma unroll 4
    for (int m = 0; m < 128; m++) {
        float wq = Wq[o * 128 + m];
        float wk = Wk[o * 192 + m];
        float wv = Wv[o * 192 + m];
#pragma unroll
        for (int ii = 0; ii < 8; ii++) {
            float nv = nl[m][ii];
            aq[ii] = fmaf(wq, nv, aq[ii]);
            ak[ii] = fmaf(wk, nv, ak[ii]);
            av[ii] = fmaf(wv, nv, av[ii]);
        }
    }
#pragma unroll
    for (int ii = 0; ii < 8; ii++) {
        vn_ws[(size_t)(i0 + ii) * 256 + o] = av[ii];
        q_l[o][ii]  = aq[ii];
        qk_l[o][ii] = aq[ii] * ak[ii];
    }
    __syncthreads();
    if (tid < 64) {
        int h = tid >> 3, ii = tid & 7;
        float s = 0.f;
        for (int a = 0; a < 32; a++) s += qk_l[h * 32 + a][ii];
        c1_ws[(i0 + ii) * 8 + h] = s;
    }
    for (int rep = 0; rep < 2; rep++) {
        int idx = rep * 256 + tid;
        int c = idx & 63, h = idx >> 6;
        float ap[8];
#pragma unroll
        for (int ii = 0; ii < 8; ii++) ap[ii] = 0.f;
        for (int a = 0; a < 32; a++) {
            float w = Wk[(h * 32 + a) * 192 + 128 + c];
#pragma unroll
            for (int ii = 0; ii < 8; ii++)
                ap[ii] = fmaf(q_l[h * 32 + a][ii], w, ap[ii]);
        }
#pragma unroll
        for (int ii = 0; ii < 8; ii++)
            P_ws[(size_t)(i0 + ii) * 512 + c * 8 + h] = ap[ii];
    }
}

// ---------------------------------------------------------------------------
// K2: per-row attention + FUSED edge-channel matmul. Block = one row i.
// pass1 (lanes=j, c-blocked by 16):
//   - sim[h,j] += P[h,c]*e[c,j]   (8 accs)
//   - eo[o]    += We[o,256+c]*e[c,j]  (64 accs, We rows uniform -> s_load)
//   - e cached to LDS as bf16 for pass2
//   eo written directly to d_out edge region (partial: missing gh_i+gh_j,
//   added later by the streaming k_eadd).
// softmax per head; pass2: T[h,c] = sum_j s[h,j]*e[c,j] as before.
__global__ __launch_bounds__(512, 2) void k_attn(
    const float* __restrict__ edges, const float* __restrict__ We,
    const float* __restrict__ ws_ro, float* __restrict__ T_ws,
    float* __restrict__ out_e) {
    __shared__ __align__(16) unsigned short epad_h[64 * 390];  // 49920 B
    __shared__ __align__(16) float sT2[NN * 8];                // 12288 B
    const float* maskf = ws_ro + WS_MASKF;
    const float* c1w   = ws_ro + WS_C1;
    const float* Pw    = ws_ro + WS_P;
    int i = blockIdx.x;
    int tid = threadIdx.x;
    int wv = tid >> 6, ln = tid & 63;
    float mask_i = maskf[i];

    if (tid < NN) {
        int j = tid;
        const float* eb = edges + (size_t)i * NN + j;
        const float* Pi = Pw + (size_t)i * 512;
        float acc[8];
        float eo[64];
#pragma unroll
        for (int h = 0; h < 8; h++) acc[h] = 0.f;
#pragma unroll
        for (int o = 0; o < 64; o++) eo[o] = 0.f;
#pragma unroll
        for (int cb = 0; cb < 4; cb++) {
            float ev[16];
#pragma unroll
            for (int t = 0; t < 16; t++)
                ev[t] = eb[(size_t)(cb * 16 + t) * NSQ];
#pragma unroll
            for (int t = 0; t < 16; t++) {
                int c = cb * 16 + t;
                unsigned u = __float_as_uint(ev[t]);
                epad_h[c * 390 + j] =
                    (unsigned short)((u + 0x7FFFu + ((u >> 16) & 1u)) >> 16);
                const float* Pc = Pi + c * 8;     // wave-uniform -> s_load
#pragma unroll
                for (int h = 0; h < 8; h++) acc[h] = fmaf(Pc[h], ev[t], acc[h]);
            }
#pragma unroll
            for (int o = 0; o < 64; o++) {
                const float* wr = We + o * 320 + 256 + cb * 16;  // uniform
#pragma unroll
                for (int t = 0; t < 16; t++)
                    eo[o] = fmaf(wr[t], ev[t], eo[o]);
            }
        }
        // partial edge_out store (coalesced per o)
        size_t ob = (size_t)i * NN + j;
#pragma unroll
        for (int o = 0; o < 64; o++) out_e[(size_t)o * NSQ + ob] = eo[o];

        float mj = maskf[j];
        const float* c1i = c1w + i * 8;
        float sv[8];
#pragma unroll
        for (int h = 0; h < 8; h++) {
            float s = (c1i[h] + acc[h]) * 0.17677669529663687f;
            sv[h] = (mj != 0.0f) ? s : -1e30f;
        }
        *reinterpret_cast<float4*>(&sT2[j * 8])     = make_float4(sv[0], sv[1], sv[2], sv[3]);
        *reinterpret_cast<float4*>(&sT2[j * 8 + 4]) = make_float4(sv[4], sv[5], sv[6], sv[7]);
    }
    __syncthreads();
    { // softmax: wave wv owns head h=wv, lanes cover j = ln + 64k
        int h = wv;
        float v[6];
#pragma unroll
        for (int k = 0; k < 6; k++) v[k] = sT2[(ln + 64 * k) * 8 + h];
        float m = v[0];
#pragma unroll
        for (int k = 1; k < 6; k++) m = fmaxf(m, v[k]);
#pragma unroll
        for (int s = 1; s < 64; s <<= 1) m = fmaxf(m, __shfl_xor(m, s));
        float ex[6]; float sum = 0.f;
#pragma unroll
        for (int k = 0; k < 6; k++) { ex[k] = __expf(v[k] - m); sum += ex[k]; }
#pragma unroll
        for (int s = 1; s < 64; s <<= 1) sum += __shfl_xor(sum, s);
        float fac = mask_i / sum;
#pragma unroll
        for (int k = 0; k < 6; k++) sT2[(ln + 64 * k) * 8 + h] = ex[k] * fac;
    }
    __syncthreads();
    // pass2: wave wv handles j in [48*wv, 48*wv+48), lane = channel c
    float t[8];
#pragma unroll
    for (int h = 0; h < 8; h++) t[h] = 0.f;
    {
        int c = ln;
        int j0 = wv * 48;
        for (int j = j0; j < j0 + 48; j++) {
            float e = __uint_as_float(((unsigned)epad_h[c * 390 + j]) << 16);
            float4 s0 = *reinterpret_cast<const float4*>(&sT2[j * 8]);
            float4 s1 = *reinterpret_cast<const float4*>(&sT2[j * 8 + 4]);
            t[0] = fmaf(s0.x, e, t[0]); t[1] = fmaf(s0.y, e, t[1]);
            t[2] = fmaf(s0.z, e, t[2]); t[3] = fmaf(s0.w, e, t[3]);
            t[4] = fmaf(s1.x, e, t[4]); t[5] = fmaf(s1.y, e, t[5]);
            t[6] = fmaf(s1.z, e, t[6]); t[7] = fmaf(s1.w, e, t[7]);
        }
    }
    __syncthreads();                       // epad_h dead; reuse as partials
    float* Tp = reinterpret_cast<float*>(epad_h);   // 8*512 floats = 16 KB
#pragma unroll
    for (int h = 0; h < 8; h++) Tp[wv * 512 + h * 64 + ln] = t[h];
    __syncthreads();
    {
        int h = tid >> 6, c = tid & 63;
        float s = 0.f;
#pragma unroll
        for (int w = 0; w < 8; w++) s += Tp[w * 512 + h * 64 + c];
        T_ws[(size_t)i * 512 + h * 64 + c] = s;
    }
}

// ---------------------------------------------------------------------------
// K3: nf[d,i] = mask_i*vn + W_v_edge @ T ; node_out = W_o@nf ; g = 0.5*W_e[:, :256]@nf
__global__ __launch_bounds__(256) void k_nf(
    const float* __restrict__ Wv, const float* __restrict__ Wo,
    const float* __restrict__ We, const float* __restrict__ ws_ro,
    float* __restrict__ gh_ws, float* __restrict__ out) {
    const float* maskf = ws_ro + WS_MASKF;
    const float* vn_ws = ws_ro + WS_VN;
    const float* T_ws  = ws_ro + WS_T;
    int i = blockIdx.x, tid = threadIdx.x;
    __shared__ float T_l[512];
    __shared__ float nf_l[256];
    T_l[tid]       = T_ws[(size_t)i * 512 + tid];
    T_l[tid + 256] = T_ws[(size_t)i * 512 + 256 + tid];
    __syncthreads();
    int d = tid, h = d >> 5;
    float a0 = 0.f, a1 = 0.f, a2 = 0.f, a3 = 0.f;
#pragma unroll
    for (int c = 0; c < 64; c += 4) {
        a0 = fmaf(Wv[d * 192 + 128 + c],     T_l[h * 64 + c],     a0);
        a1 = fmaf(Wv[d * 192 + 128 + c + 1], T_l[h * 64 + c + 1], a1);
        a2 = fmaf(Wv[d * 192 + 128 + c + 2], T_l[h * 64 + c + 2], a2);
        a3 = fmaf(Wv[d * 192 + 128 + c + 3], T_l[h * 64 + c + 3], a3);
    }
    nf_l[d] = maskf[i] * vn_ws[(size_t)i * 256 + d] + ((a0 + a1) + (a2 + a3));
    __syncthreads();
    if (tid < 128) {
        int o = tid;
        float b0 = 0.f, b1 = 0.f, b2 = 0.f, b3 = 0.f;
#pragma unroll 8
        for (int dd = 0; dd < 256; dd += 4) {
            b0 = fmaf(Wo[o * 256 + dd],     nf_l[dd],     b0);
            b1 = fmaf(Wo[o * 256 + dd + 1], nf_l[dd + 1], b1);
            b2 = fmaf(Wo[o * 256 + dd + 2], nf_l[dd + 2], b2);
            b3 = fmaf(Wo[o * 256 + dd + 3], nf_l[dd + 3], b3);
        }
        out[o * NN + i] = (b0 + b1) + (b2 + b3);
    } else if (tid < 192) {
        int o = tid - 128;
        float b0 = 0.f, b1 = 0.f, b2 = 0.f, b3 = 0.f;
#pragma unroll 8
        for (int dd = 0; dd < 256; dd += 4) {
            b0 = fmaf(We[o * 320 + dd],     nf_l[dd],     b0);
            b1 = fmaf(We[o * 320 + dd + 1], nf_l[dd + 1], b1);
            b2 = fmaf(We[o * 320 + dd + 2], nf_l[dd + 2], b2);
            b3 = fmaf(We[o * 320 + dd + 3], nf_l[dd + 3], b3);
        }
        gh_ws[o * NN + i] = 0.5f * ((b0 + b1) + (b2 + b3));
    }
}

// ---------------------------------------------------------------------------
// K4: streaming RMW — out_e[o,i,j] += gh[o,i] + gh[o,j].
// Block = (i, og of 16 o's); thread = j. gj[16] prefetched; gi uniform ->
// s_load; loads/stores fully coalesced. ~40 VGPR -> 8 waves/SIMD, 9216 waves.
__global__ __launch_bounds__(384) void k_eadd(
    const float* __restrict__ gh_ws, float* __restrict__ out_e) {
    int i = blockIdx.x, og = blockIdx.y, j = threadIdx.x;
    float gj[16];
    const float* gb = gh_ws + og * 16 * NN + j;
#pragma unroll
    for (int t = 0; t < 16; t++) gj[t] = gb[t * NN];
    size_t ob = (size_t)i * NN + j;
#pragma unroll 4
    for (int t = 0; t < 16; t++) {
        int o = og * 16 + t;
        float gi = gh_ws[o * NN + i];          // uniform -> s_load
        float* p = out_e + (size_t)o * NSQ + ob;
        *p = *p + gi + gj[t];
    }
}

// ---------------------------------------------------------------------------
extern "C" void kernel_launch(void* const* d_in, const int* in_sizes, int n_in,
                              void* d_out, int out_size, void* d_ws, size_t ws_size,
                              hipStream_t stream) {
    const float* nodes = (const float*)d_in[0];
    const float* edges = (const float*)d_in[1];
    const unsigned int* mask = (const unsigned int*)d_in[2];
    const float* Wq = (const float*)d_in[3];
    const float* Wk = (const float*)d_in[4];
    const float* Wv = (const float*)d_in[5];
    const float* Wo = (const float*)d_in[6];
    const float* We = (const float*)d_in[7];
    float* out = (float*)d_out;
    float* ws  = (float*)d_ws;
    float* out_e = out + 128 * NN;

    hipLaunchKernelGGL(k_proj, dim3(49), dim3(256), 0, stream,
                       nodes, Wq, Wk, Wv, mask, ws);
    hipLaunchKernelGGL(k_attn, dim3(384), dim3(512), 0, stream,
                       edges, We, ws, ws + WS_T, out_e);
    hipLaunchKernelGGL(k_nf, dim3(384), dim3(256), 0, stream, Wv, Wo, We, ws,
                       ws + WS_GH, out);
    hipLaunchKernelGGL(k_eadd, dim3(384, 4), dim3(384), 0, stream,
                       ws + WS_GH, out_e);
}

// Round 4
// 179.148 us; speedup vs baseline: 1.2830x; 1.2830x over previous
//
#include <hip/hip_runtime.h>
#include <math.h>

#define NN 384
#define NSQ (NN*NN)          // 147456

// workspace float offsets
#define WS_MASKF 0           // 384
#define WS_C1    384         // 384*8   = 3072
#define WS_P     3456        // 384*512 = 196608
#define WS_VN    200064      // 384*256 = 98304
#define WS_T     298368      // 384*512 = 196608
#define WS_GH    494976      // 64*384  = 24576
#define WS_WT    519552      // 64*64   = 4096  (We edge block, transposed [c][o])
// total 523648 floats = ~2.09 MB

// ---------------------------------------------------------------------------
// K1: q/kn/vn projections + c1[h,i] = sum_a q*kn, P[h,c,i] = sum_a q*Wk_edge.
// Blocks 0..47: 8 columns i each. Block 48: mask normalize. Block 49: We^T.
__global__ __launch_bounds__(256) void k_proj(
    const float* __restrict__ nodes, const float* __restrict__ Wq,
    const float* __restrict__ Wk, const float* __restrict__ Wv,
    const float* __restrict__ We, const unsigned int* __restrict__ mi,
    float* __restrict__ ws) {
    int tid = threadIdx.x;
    if (blockIdx.x == 48) {
        // mask -> float {0,1}; detect int32 vs packed-byte delivery.
        __shared__ int bytemode;
        if (tid == 0) bytemode = 0;
        __syncthreads();
        unsigned v0 = mi[tid];
        unsigned v1 = (tid < 128) ? mi[256 + tid] : 0u;
        if (v0 > 1u || v1 > 1u) bytemode = 1;   // benign race
        __syncthreads();
        float* maskf = ws + WS_MASKF;
        for (int j = tid; j < NN; j += 256) {
            int on;
            if (bytemode) on = (((const unsigned char*)mi)[j] != 0);
            else          on = (mi[j] != 0u);
            maskf[j] = on ? 1.0f : 0.0f;
        }
        return;
    }
    if (blockIdx.x == 49) {
        // transpose We[:, 256:320] -> Wt[c][o] so k_edge can s_load 16
        // contiguous weights per (c, o-group).
        float* Wt = ws + WS_WT;
        for (int idx = tid; idx < 4096; idx += 256) {
            int c = idx >> 6, o = idx & 63;
            Wt[c * 64 + o] = We[o * 320 + 256 + c];
        }
        return;
    }
    float* c1_ws = ws + WS_C1;
    float* P_ws  = ws + WS_P;
    float* vn_ws = ws + WS_VN;
    int i0 = blockIdx.x * 8;
    __shared__ float nl[128][8];
    __shared__ float q_l[256][8];
    __shared__ float qk_l[256][8];
    for (int idx = tid; idx < 1024; idx += 256) {
        int m = idx >> 3, ii = idx & 7;
        nl[m][ii] = nodes[m * NN + i0 + ii];
    }
    __syncthreads();
    int o = tid;
    float aq[8], ak[8], av[8];
#pragma unroll
    for (int ii = 0; ii < 8; ii++) { aq[ii] = 0.f; ak[ii] = 0.f; av[ii] = 0.f; }
#pragma unroll 4
    for (int m = 0; m < 128; m++) {
        float wq = Wq[o * 128 + m];
        float wk = Wk[o * 192 + m];
        float wv = Wv[o * 192 + m];
#pragma unroll
        for (int ii = 0; ii < 8; ii++) {
            float nv = nl[m][ii];
            aq[ii] = fmaf(wq, nv, aq[ii]);
            ak[ii] = fmaf(wk, nv, ak[ii]);
            av[ii] = fmaf(wv, nv, av[ii]);
        }
    }
#pragma unroll
    for (int ii = 0; ii < 8; ii++) {
        vn_ws[(size_t)(i0 + ii) * 256 + o] = av[ii];
        q_l[o][ii]  = aq[ii];
        qk_l[o][ii] = aq[ii] * ak[ii];
    }
    __syncthreads();
    if (tid < 64) {
        int h = tid >> 3, ii = tid & 7;
        float s = 0.f;
        for (int a = 0; a < 32; a++) s += qk_l[h * 32 + a][ii];
        c1_ws[(i0 + ii) * 8 + h] = s;
    }
    for (int rep = 0; rep < 2; rep++) {
        int idx = rep * 256 + tid;
        int c = idx & 63, h = idx >> 6;
        float ap[8];
#pragma unroll
        for (int ii = 0; ii < 8; ii++) ap[ii] = 0.f;
        for (int a = 0; a < 32; a++) {
            float w = Wk[(h * 32 + a) * 192 + 128 + c];
#pragma unroll
            for (int ii = 0; ii < 8; ii++)
                ap[ii] = fmaf(q_l[h * 32 + a][ii], w, ap[ii]);
        }
#pragma unroll
        for (int ii = 0; ii < 8; ii++)
            P_ws[(size_t)(i0 + ii) * 512 + c * 8 + h] = ap[ii];
    }
}

// ---------------------------------------------------------------------------
// K2: per-row attention (R2-proven form — no eo fusion, no spill risk).
// Block = one row i, 512 threads.
// pass1 (lanes=j): sim[h,j] = (c1 + sum_c P[h,c]*e[c,j]) * rsqrt(A), masked.
//   Edge values also cached to LDS as bf16 (62 KB total LDS -> 2 blocks/CU).
// softmax per head (one wave per head, butterfly reduce).
// pass2 (lanes=c): T[h,c] = sum_j s[h,j]*e[c,j], partial per wave, combined.
__global__ __launch_bounds__(512) void k_attn(
    const float* __restrict__ edges, const float* __restrict__ ws_ro,
    float* __restrict__ T_ws) {
    __shared__ __align__(16) unsigned short epad_h[64 * 390];  // 49920 B
    __shared__ __align__(16) float sT2[NN * 8];                // 12288 B
    const float* maskf = ws_ro + WS_MASKF;
    const float* c1w   = ws_ro + WS_C1;
    const float* Pw    = ws_ro + WS_P;
    int i = blockIdx.x;
    int tid = threadIdx.x;
    int wv = tid >> 6, ln = tid & 63;
    float mask_i = maskf[i];

    if (tid < NN) {
        int j = tid;
        const float* eb = edges + (size_t)i * NN + j;
        const float* Pi = Pw + (size_t)i * 512;
        float acc[8];
#pragma unroll
        for (int h = 0; h < 8; h++) acc[h] = 0.f;
#pragma unroll 4
        for (int c = 0; c < 64; c++) {
            float e = eb[(size_t)c * NSQ];
            unsigned u = __float_as_uint(e);
            epad_h[c * 390 + j] =
                (unsigned short)((u + 0x7FFFu + ((u >> 16) & 1u)) >> 16);
            const float* Pc = Pi + c * 8;     // wave-uniform -> s_load
#pragma unroll
            for (int h = 0; h < 8; h++) acc[h] = fmaf(Pc[h], e, acc[h]);
        }
        float mj = maskf[j];
        const float* c1i = c1w + i * 8;
        float sv[8];
#pragma unroll
        for (int h = 0; h < 8; h++) {
            float s = (c1i[h] + acc[h]) * 0.17677669529663687f;
            sv[h] = (mj != 0.0f) ? s : -1e30f;
        }
        *reinterpret_cast<float4*>(&sT2[j * 8])     = make_float4(sv[0], sv[1], sv[2], sv[3]);
        *reinterpret_cast<float4*>(&sT2[j * 8 + 4]) = make_float4(sv[4], sv[5], sv[6], sv[7]);
    }
    __syncthreads();
    { // softmax: wave wv owns head h=wv, lanes cover j = ln + 64k
        int h = wv;
        float v[6];
#pragma unroll
        for (int k = 0; k < 6; k++) v[k] = sT2[(ln + 64 * k) * 8 + h];
        float m = v[0];
#pragma unroll
        for (int k = 1; k < 6; k++) m = fmaxf(m, v[k]);
#pragma unroll
        for (int s = 1; s < 64; s <<= 1) m = fmaxf(m, __shfl_xor(m, s));
        float ex[6]; float sum = 0.f;
#pragma unroll
        for (int k = 0; k < 6; k++) { ex[k] = __expf(v[k] - m); sum += ex[k]; }
#pragma unroll
        for (int s = 1; s < 64; s <<= 1) sum += __shfl_xor(sum, s);
        float fac = mask_i / sum;
#pragma unroll
        for (int k = 0; k < 6; k++) sT2[(ln + 64 * k) * 8 + h] = ex[k] * fac;
    }
    __syncthreads();
    // pass2: wave wv handles j in [48*wv, 48*wv+48), lane = channel c
    float t[8];
#pragma unroll
    for (int h = 0; h < 8; h++) t[h] = 0.f;
    {
        int c = ln;
        int j0 = wv * 48;
        for (int j = j0; j < j0 + 48; j++) {
            float e = __uint_as_float(((unsigned)epad_h[c * 390 + j]) << 16);
            float4 s0 = *reinterpret_cast<const float4*>(&sT2[j * 8]);
            float4 s1 = *reinterpret_cast<const float4*>(&sT2[j * 8 + 4]);
            t[0] = fmaf(s0.x, e, t[0]); t[1] = fmaf(s0.y, e, t[1]);
            t[2] = fmaf(s0.z, e, t[2]); t[3] = fmaf(s0.w, e, t[3]);
            t[4] = fmaf(s1.x, e, t[4]); t[5] = fmaf(s1.y, e, t[5]);
            t[6] = fmaf(s1.z, e, t[6]); t[7] = fmaf(s1.w, e, t[7]);
        }
    }
    __syncthreads();                       // epad_h dead; reuse as partials
    float* Tp = reinterpret_cast<float*>(epad_h);   // 8*512 floats = 16 KB
#pragma unroll
    for (int h = 0; h < 8; h++) Tp[wv * 512 + h * 64 + ln] = t[h];
    __syncthreads();
    {
        int h = tid >> 6, c = tid & 63;
        float s = 0.f;
#pragma unroll
        for (int w = 0; w < 8; w++) s += Tp[w * 512 + h * 64 + c];
        T_ws[(size_t)i * 512 + h * 64 + c] = s;
    }
}

// ---------------------------------------------------------------------------
// K3: nf[d,i] = mask_i*vn + W_v_edge @ T ; node_out = W_o@nf ; g = 0.5*W_e[:, :256]@nf
__global__ __launch_bounds__(256) void k_nf(
    const float* __restrict__ Wv, const float* __restrict__ Wo,
    const float* __restrict__ We, const float* __restrict__ ws_ro,
    float* __restrict__ gh_ws, float* __restrict__ out) {
    const float* maskf = ws_ro + WS_MASKF;
    const float* vn_ws = ws_ro + WS_VN;
    const float* T_ws  = ws_ro + WS_T;
    int i = blockIdx.x, tid = threadIdx.x;
    __shared__ float T_l[512];
    __shared__ float nf_l[256];
    T_l[tid]       = T_ws[(size_t)i * 512 + tid];
    T_l[tid + 256] = T_ws[(size_t)i * 512 + 256 + tid];
    __syncthreads();
    int d = tid, h = d >> 5;
    float a0 = 0.f, a1 = 0.f, a2 = 0.f, a3 = 0.f;
#pragma unroll
    for (int c = 0; c < 64; c += 4) {
        a0 = fmaf(Wv[d * 192 + 128 + c],     T_l[h * 64 + c],     a0);
        a1 = fmaf(Wv[d * 192 + 128 + c + 1], T_l[h * 64 + c + 1], a1);
        a2 = fmaf(Wv[d * 192 + 128 + c + 2], T_l[h * 64 + c + 2], a2);
        a3 = fmaf(Wv[d * 192 + 128 + c + 3], T_l[h * 64 + c + 3], a3);
    }
    nf_l[d] = maskf[i] * vn_ws[(size_t)i * 256 + d] + ((a0 + a1) + (a2 + a3));
    __syncthreads();
    if (tid < 128) {
        int o = tid;
        float b0 = 0.f, b1 = 0.f, b2 = 0.f, b3 = 0.f;
#pragma unroll 8
        for (int dd = 0; dd < 256; dd += 4) {
            b0 = fmaf(Wo[o * 256 + dd],     nf_l[dd],     b0);
            b1 = fmaf(Wo[o * 256 + dd + 1], nf_l[dd + 1], b1);
            b2 = fmaf(Wo[o * 256 + dd + 2], nf_l[dd + 2], b2);
            b3 = fmaf(Wo[o * 256 + dd + 3], nf_l[dd + 3], b3);
        }
        out[o * NN + i] = (b0 + b1) + (b2 + b3);
    } else if (tid < 192) {
        int o = tid - 128;
        float b0 = 0.f, b1 = 0.f, b2 = 0.f, b3 = 0.f;
#pragma unroll 8
        for (int dd = 0; dd < 256; dd += 4) {
            b0 = fmaf(We[o * 320 + dd],     nf_l[dd],     b0);
            b1 = fmaf(We[o * 320 + dd + 1], nf_l[dd + 1], b1);
            b2 = fmaf(We[o * 320 + dd + 2], nf_l[dd + 2], b2);
            b3 = fmaf(We[o * 320 + dd + 3], nf_l[dd + 3], b3);
        }
        gh_ws[o * NN + i] = 0.5f * ((b0 + b1) + (b2 + b3));
    }
}

// ---------------------------------------------------------------------------
// K4: FINAL edge write (single pass, no RMW):
//   out_e[o,i,j] = gh[o,i] + gh[o,j] + sum_c Wt[c][o]*edges[c,i,j]
// Block = (i, og of 16 o's); thread = j. Only eo[16]+gj[16] live -> ~45 VGPR
// (the e[64]/eo[64] spill trap from R1/R3 is structurally avoided).
// Edges are L3/L2-warm (2nd read, 37.7 MB total fits L3). Wt row per c is
// uniform+contiguous -> one s_load_dwordx16. Stores fully coalesced.
__global__ __launch_bounds__(384) void k_edge(
    const float* __restrict__ edges, const float* __restrict__ ws_ro,
    float* __restrict__ out_e) {
    const float* Wt = ws_ro + WS_WT;
    const float* gh = ws_ro + WS_GH;
    int i = blockIdx.x, og = blockIdx.y, j = threadIdx.x;
    float gj[16];
    const float* gb = gh + og * 16 * NN + j;
#pragma unroll
    for (int t = 0; t < 16; t++) gj[t] = gb[t * NN];
    float eo[16];
#pragma unroll
    for (int t = 0; t < 16; t++) eo[t] = 0.f;
    const float* eb = edges + (size_t)i * NN + j;
    const float* wtb = Wt + og * 16;
#pragma unroll 4
    for (int c = 0; c < 64; c++) {
        float e = eb[(size_t)c * NSQ];
        const float* wr = wtb + c * 64;    // uniform -> s_load_dwordx16
#pragma unroll
        for (int t = 0; t < 16; t++) eo[t] = fmaf(wr[t], e, eo[t]);
    }
    size_t ob = (size_t)i * NN + j;
    const float* gib = gh + og * 16 * NN + i;
#pragma unroll
    for (int t = 0; t < 16; t++) {
        float gi = gib[t * NN];            // uniform -> s_load
        out_e[(size_t)(og * 16 + t) * NSQ + ob] = eo[t] + gi + gj[t];
    }
}

// ---------------------------------------------------------------------------
extern "C" void kernel_launch(void* const* d_in, const int* in_sizes, int n_in,
                              void* d_out, int out_size, void* d_ws, size_t ws_size,
                              hipStream_t stream) {
    const float* nodes = (const float*)d_in[0];
    const float* edges = (const float*)d_in[1];
    const unsigned int* mask = (const unsigned int*)d_in[2];
    const float* Wq = (const float*)d_in[3];
    const float* Wk = (const float*)d_in[4];
    const float* Wv = (const float*)d_in[5];
    const float* Wo = (const float*)d_in[6];
    const float* We = (const float*)d_in[7];
    float* out = (float*)d_out;
    float* ws  = (float*)d_ws;
    float* out_e = out + 128 * NN;

    hipLaunchKernelGGL(k_proj, dim3(50), dim3(256), 0, stream,
                       nodes, Wq, Wk, Wv, We, mask, ws);
    hipLaunchKernelGGL(k_attn, dim3(384), dim3(512), 0, stream,
                       edges, ws, ws + WS_T);
    hipLaunchKernelGGL(k_nf, dim3(384), dim3(256), 0, stream, Wv, Wo, We, ws,
                       ws + WS_GH, out);
    hipLaunchKernelGGL(k_edge, dim3(384, 4), dim3(384), 0, stream,
                       edges, ws, out_e);
}

// Round 5
// 176.776 us; speedup vs baseline: 1.3002x; 1.0134x over previous
//
#include <hip/hip_runtime.h>
#include <math.h>

#define NN 384
#define NSQ (NN*NN)          // 147456

// workspace float offsets
#define WS_MASKF 0           // 384
#define WS_C1    384         // 384*8   = 3072
#define WS_P     3456        // 384*512 = 196608
#define WS_VN    200064      // 384*256 = 98304
#define WS_T     298368      // 384*512 = 196608
#define WS_GH    494976      // 64*384  = 24576
#define WS_WT    519552      // 64*64   = 4096  (We edge block, transposed [c][o])
// total 523648 floats = ~2.09 MB

// ---------------------------------------------------------------------------
// K1: q/kn/vn projections + c1[h,i] = sum_a q*kn, P[h,c,i] = sum_a q*Wk_edge.
// Blocks 0..47: 8 columns i each. Block 48: mask normalize. Block 49: We^T.
__global__ __launch_bounds__(256) void k_proj(
    const float* __restrict__ nodes, const float* __restrict__ Wq,
    const float* __restrict__ Wk, const float* __restrict__ Wv,
    const float* __restrict__ We, const unsigned int* __restrict__ mi,
    float* __restrict__ ws) {
    int tid = threadIdx.x;
    if (blockIdx.x == 48) {
        // mask -> float {0,1}; detect int32 vs packed-byte delivery.
        __shared__ int bytemode;
        if (tid == 0) bytemode = 0;
        __syncthreads();
        unsigned v0 = mi[tid];
        unsigned v1 = (tid < 128) ? mi[256 + tid] : 0u;
        if (v0 > 1u || v1 > 1u) bytemode = 1;   // benign race
        __syncthreads();
        float* maskf = ws + WS_MASKF;
        for (int j = tid; j < NN; j += 256) {
            int on;
            if (bytemode) on = (((const unsigned char*)mi)[j] != 0);
            else          on = (mi[j] != 0u);
            maskf[j] = on ? 1.0f : 0.0f;
        }
        return;
    }
    if (blockIdx.x == 49) {
        // transpose We[:, 256:320] -> Wt[c][o] so k_edge can s_load 16
        // contiguous weights per (c, o-group).
        float* Wt = ws + WS_WT;
        for (int idx = tid; idx < 4096; idx += 256) {
            int c = idx >> 6, o = idx & 63;
            Wt[c * 64 + o] = We[o * 320 + 256 + c];
        }
        return;
    }
    float* c1_ws = ws + WS_C1;
    float* P_ws  = ws + WS_P;
    float* vn_ws = ws + WS_VN;
    int i0 = blockIdx.x * 8;
    __shared__ float nl[128][8];
    __shared__ float q_l[256][8];
    __shared__ float qk_l[256][8];
    for (int idx = tid; idx < 1024; idx += 256) {
        int m = idx >> 3, ii = idx & 7;
        nl[m][ii] = nodes[m * NN + i0 + ii];
    }
    __syncthreads();
    int o = tid;
    float aq[8], ak[8], av[8];
#pragma unroll
    for (int ii = 0; ii < 8; ii++) { aq[ii] = 0.f; ak[ii] = 0.f; av[ii] = 0.f; }
#pragma unroll 4
    for (int m = 0; m < 128; m++) {
        float wq = Wq[o * 128 + m];
        float wk = Wk[o * 192 + m];
        float wv = Wv[o * 192 + m];
#pragma unroll
        for (int ii = 0; ii < 8; ii++) {
            float nv = nl[m][ii];
            aq[ii] = fmaf(wq, nv, aq[ii]);
            ak[ii] = fmaf(wk, nv, ak[ii]);
            av[ii] = fmaf(wv, nv, av[ii]);
        }
    }
#pragma unroll
    for (int ii = 0; ii < 8; ii++) {
        vn_ws[(size_t)(i0 + ii) * 256 + o] = av[ii];
        q_l[o][ii]  = aq[ii];
        qk_l[o][ii] = aq[ii] * ak[ii];
    }
    __syncthreads();
    if (tid < 64) {
        int h = tid >> 3, ii = tid & 7;
        float s = 0.f;
        for (int a = 0; a < 32; a++) s += qk_l[h * 32 + a][ii];
        c1_ws[(i0 + ii) * 8 + h] = s;
    }
    for (int rep = 0; rep < 2; rep++) {
        int idx = rep * 256 + tid;
        int c = idx & 63, h = idx >> 6;
        float ap[8];
#pragma unroll
        for (int ii = 0; ii < 8; ii++) ap[ii] = 0.f;
        for (int a = 0; a < 32; a++) {
            float w = Wk[(h * 32 + a) * 192 + 128 + c];
#pragma unroll
            for (int ii = 0; ii < 8; ii++)
                ap[ii] = fmaf(q_l[h * 32 + a][ii], w, ap[ii]);
        }
#pragma unroll
        for (int ii = 0; ii < 8; ii++)
            P_ws[(size_t)(i0 + ii) * 512 + c * 8 + h] = ap[ii];
    }
}

// ---------------------------------------------------------------------------
// K2: per-row attention. Block = one row i, 512 threads.
// pass1 (lanes=j, c-batched by 16): ev[16] loads issued back-to-back (16
//   outstanding -> hides ~400cy L2/L3 latency that serialized the R4 version),
//   then consumed: sim[h,j] += P[h,c]*ev, e cached to LDS as bf16.
//   VGPR ~55 (no eo[] -> no spill; R3's trap avoided).
// softmax per head (one wave per head, butterfly reduce).
// pass2 (lanes=c): T[h,c] = sum_j s[h,j]*e[c,j], partial per wave, combined.
__global__ __launch_bounds__(512) void k_attn(
    const float* __restrict__ edges, const float* __restrict__ ws_ro,
    float* __restrict__ T_ws) {
    __shared__ __align__(16) unsigned short epad_h[64 * 390];  // 49920 B
    __shared__ __align__(16) float sT2[NN * 8];                // 12288 B
    const float* maskf = ws_ro + WS_MASKF;
    const float* c1w   = ws_ro + WS_C1;
    const float* Pw    = ws_ro + WS_P;
    int i = blockIdx.x;
    int tid = threadIdx.x;
    int wv = tid >> 6, ln = tid & 63;
    float mask_i = maskf[i];

    if (tid < NN) {
        int j = tid;
        const float* eb = edges + (size_t)i * NN + j;
        const float* Pi = Pw + (size_t)i * 512;
        float acc[8];
#pragma unroll
        for (int h = 0; h < 8; h++) acc[h] = 0.f;
#pragma unroll
        for (int cb = 0; cb < 4; cb++) {
            float ev[16];
#pragma unroll
            for (int t = 0; t < 16; t++)
                ev[t] = eb[(size_t)(cb * 16 + t) * NSQ];
#pragma unroll
            for (int t = 0; t < 16; t++) {
                int c = cb * 16 + t;
                unsigned u = __float_as_uint(ev[t]);
                epad_h[c * 390 + j] =
                    (unsigned short)((u + 0x7FFFu + ((u >> 16) & 1u)) >> 16);
                const float* Pc = Pi + c * 8;     // wave-uniform -> s_load
#pragma unroll
                for (int h = 0; h < 8; h++) acc[h] = fmaf(Pc[h], ev[t], acc[h]);
            }
        }
        float mj = maskf[j];
        const float* c1i = c1w + i * 8;
        float sv[8];
#pragma unroll
        for (int h = 0; h < 8; h++) {
            float s = (c1i[h] + acc[h]) * 0.17677669529663687f;
            sv[h] = (mj != 0.0f) ? s : -1e30f;
        }
        *reinterpret_cast<float4*>(&sT2[j * 8])     = make_float4(sv[0], sv[1], sv[2], sv[3]);
        *reinterpret_cast<float4*>(&sT2[j * 8 + 4]) = make_float4(sv[4], sv[5], sv[6], sv[7]);
    }
    __syncthreads();
    { // softmax: wave wv owns head h=wv, lanes cover j = ln + 64k
        int h = wv;
        float v[6];
#pragma unroll
        for (int k = 0; k < 6; k++) v[k] = sT2[(ln + 64 * k) * 8 + h];
        float m = v[0];
#pragma unroll
        for (int k = 1; k < 6; k++) m = fmaxf(m, v[k]);
#pragma unroll
        for (int s = 1; s < 64; s <<= 1) m = fmaxf(m, __shfl_xor(m, s));
        float ex[6]; float sum = 0.f;
#pragma unroll
        for (int k = 0; k < 6; k++) { ex[k] = __expf(v[k] - m); sum += ex[k]; }
#pragma unroll
        for (int s = 1; s < 64; s <<= 1) sum += __shfl_xor(sum, s);
        float fac = mask_i / sum;
#pragma unroll
        for (int k = 0; k < 6; k++) sT2[(ln + 64 * k) * 8 + h] = ex[k] * fac;
    }
    __syncthreads();
    // pass2: wave wv handles j in [48*wv, 48*wv+48), lane = channel c
    float t[8];
#pragma unroll
    for (int h = 0; h < 8; h++) t[h] = 0.f;
    {
        int c = ln;
        int j0 = wv * 48;
        for (int j = j0; j < j0 + 48; j++) {
            float e = __uint_as_float(((unsigned)epad_h[c * 390 + j]) << 16);
            float4 s0 = *reinterpret_cast<const float4*>(&sT2[j * 8]);
            float4 s1 = *reinterpret_cast<const float4*>(&sT2[j * 8 + 4]);
            t[0] = fmaf(s0.x, e, t[0]); t[1] = fmaf(s0.y, e, t[1]);
            t[2] = fmaf(s0.z, e, t[2]); t[3] = fmaf(s0.w, e, t[3]);
            t[4] = fmaf(s1.x, e, t[4]); t[5] = fmaf(s1.y, e, t[5]);
            t[6] = fmaf(s1.z, e, t[6]); t[7] = fmaf(s1.w, e, t[7]);
        }
    }
    __syncthreads();                       // epad_h dead; reuse as partials
    float* Tp = reinterpret_cast<float*>(epad_h);   // 8*512 floats = 16 KB
#pragma unroll
    for (int h = 0; h < 8; h++) Tp[wv * 512 + h * 64 + ln] = t[h];
    __syncthreads();
    {
        int h = tid >> 6, c = tid & 63;
        float s = 0.f;
#pragma unroll
        for (int w = 0; w < 8; w++) s += Tp[w * 512 + h * 64 + c];
        T_ws[(size_t)i * 512 + h * 64 + c] = s;
    }
}

// ---------------------------------------------------------------------------
// K3: nf[d,i] = mask_i*vn + W_v_edge @ T ; node_out = W_o@nf ; g = 0.5*W_e[:, :256]@nf
__global__ __launch_bounds__(256) void k_nf(
    const float* __restrict__ Wv, const float* __restrict__ Wo,
    const float* __restrict__ We, const float* __restrict__ ws_ro,
    float* __restrict__ gh_ws, float* __restrict__ out) {
    const float* maskf = ws_ro + WS_MASKF;
    const float* vn_ws = ws_ro + WS_VN;
    const float* T_ws  = ws_ro + WS_T;
    int i = blockIdx.x, tid = threadIdx.x;
    __shared__ float T_l[512];
    __shared__ float nf_l[256];
    T_l[tid]       = T_ws[(size_t)i * 512 + tid];
    T_l[tid + 256] = T_ws[(size_t)i * 512 + 256 + tid];
    __syncthreads();
    int d = tid, h = d >> 5;
    float a0 = 0.f, a1 = 0.f, a2 = 0.f, a3 = 0.f;
#pragma unroll
    for (int c = 0; c < 64; c += 4) {
        a0 = fmaf(Wv[d * 192 + 128 + c],     T_l[h * 64 + c],     a0);
        a1 = fmaf(Wv[d * 192 + 128 + c + 1], T_l[h * 64 + c + 1], a1);
        a2 = fmaf(Wv[d * 192 + 128 + c + 2], T_l[h * 64 + c + 2], a2);
        a3 = fmaf(Wv[d * 192 + 128 + c + 3], T_l[h * 64 + c + 3], a3);
    }
    nf_l[d] = maskf[i] * vn_ws[(size_t)i * 256 + d] + ((a0 + a1) + (a2 + a3));
    __syncthreads();
    if (tid < 128) {
        int o = tid;
        float b0 = 0.f, b1 = 0.f, b2 = 0.f, b3 = 0.f;
#pragma unroll 8
        for (int dd = 0; dd < 256; dd += 4) {
            b0 = fmaf(Wo[o * 256 + dd],     nf_l[dd],     b0);
            b1 = fmaf(Wo[o * 256 + dd + 1], nf_l[dd + 1], b1);
            b2 = fmaf(Wo[o * 256 + dd + 2], nf_l[dd + 2], b2);
            b3 = fmaf(Wo[o * 256 + dd + 3], nf_l[dd + 3], b3);
        }
        out[o * NN + i] = (b0 + b1) + (b2 + b3);
    } else if (tid < 192) {
        int o = tid - 128;
        float b0 = 0.f, b1 = 0.f, b2 = 0.f, b3 = 0.f;
#pragma unroll 8
        for (int dd = 0; dd < 256; dd += 4) {
            b0 = fmaf(We[o * 320 + dd],     nf_l[dd],     b0);
            b1 = fmaf(We[o * 320 + dd + 1], nf_l[dd + 1], b1);
            b2 = fmaf(We[o * 320 + dd + 2], nf_l[dd + 2], b2);
            b3 = fmaf(We[o * 320 + dd + 3], nf_l[dd + 3], b3);
        }
        gh_ws[o * NN + i] = 0.5f * ((b0 + b1) + (b2 + b3));
    }
}

// ---------------------------------------------------------------------------
// K4: FINAL edge write (single pass, no RMW):
//   out_e[o,i,j] = gh[o,i] + gh[o,j] + sum_c Wt[c][o]*edges[c,i,j]
// Block = (i, og of 16 o's); thread = j. Only eo[16]+gj[16] live -> ~45 VGPR
// (the e[64]/eo[64] spill trap from R1/R3 is structurally avoided).
// Edges are L3/L2-warm (2nd read, 37.7 MB total fits L3). Wt row per c is
// uniform+contiguous -> one s_load_dwordx16. Stores fully coalesced.
__global__ __launch_bounds__(384) void k_edge(
    const float* __restrict__ edges, const float* __restrict__ ws_ro,
    float* __restrict__ out_e) {
    const float* Wt = ws_ro + WS_WT;
    const float* gh = ws_ro + WS_GH;
    int i = blockIdx.x, og = blockIdx.y, j = threadIdx.x;
    float gj[16];
    const float* gb = gh + og * 16 * NN + j;
#pragma unroll
    for (int t = 0; t < 16; t++) gj[t] = gb[t * NN];
    float eo[16];
#pragma unroll
    for (int t = 0; t < 16; t++) eo[t] = 0.f;
    const float* eb = edges + (size_t)i * NN + j;
    const float* wtb = Wt + og * 16;
#pragma unroll 4
    for (int c = 0; c < 64; c++) {
        float e = eb[(size_t)c * NSQ];
        const float* wr = wtb + c * 64;    // uniform -> s_load_dwordx16
#pragma unroll
        for (int t = 0; t < 16; t++) eo[t] = fmaf(wr[t], e, eo[t]);
    }
    size_t ob = (size_t)i * NN + j;
    const float* gib = gh + og * 16 * NN + i;
#pragma unroll
    for (int t = 0; t < 16; t++) {
        float gi = gib[t * NN];            // uniform -> s_load
        out_e[(size_t)(og * 16 + t) * NSQ + ob] = eo[t] + gi + gj[t];
    }
}

// ---------------------------------------------------------------------------
extern "C" void kernel_launch(void* const* d_in, const int* in_sizes, int n_in,
                              void* d_out, int out_size, void* d_ws, size_t ws_size,
                              hipStream_t stream) {
    const float* nodes = (const float*)d_in[0];
    const float* edges = (const float*)d_in[1];
    const unsigned int* mask = (const unsigned int*)d_in[2];
    const float* Wq = (const float*)d_in[3];
    const float* Wk = (const float*)d_in[4];
    const float* Wv = (const float*)d_in[5];
    const float* Wo = (const float*)d_in[6];
    const float* We = (const float*)d_in[7];
    float* out = (float*)d_out;
    float* ws  = (float*)d_ws;
    float* out_e = out + 128 * NN;

    hipLaunchKernelGGL(k_proj, dim3(50), dim3(256), 0, stream,
                       nodes, Wq, Wk, Wv, We, mask, ws);
    hipLaunchKernelGGL(k_attn, dim3(384), dim3(512), 0, stream,
                       edges, ws, ws + WS_T);
    hipLaunchKernelGGL(k_nf, dim3(384), dim3(256), 0, stream, Wv, Wo, We, ws,
                       ws + WS_GH, out);
    hipLaunchKernelGGL(k_edge, dim3(384, 4), dim3(384), 0, stream,
                       edges, ws, out_e);
}

// Round 6
// 172.397 us; speedup vs baseline: 1.3332x; 1.0254x over previous
//
#include <hip/hip_runtime.h>
#include <math.h>

#define NN 384
#define NSQ (NN*NN)          // 147456

// workspace float offsets
#define WS_MASKF 0           // 384
#define WS_C1    384         // 384*8   = 3072
#define WS_P     3456        // 384*512 = 196608
#define WS_VN    200064      // 384*256 = 98304
#define WS_T     298368      // 384*512 = 196608
#define WS_GH    494976      // 64*384  = 24576
#define WS_WT    519552      // 64*64   = 4096   We[:,256:320]^T  [c][o]
#define WS_WOT   523648      // 256*128 = 32768  Wo^T            [dd][o]
#define WS_WVE   556416      // 64*256  = 16384  Wv[:,128:192]^T [c][d]
#define WS_WEN   572800      // 256*64  = 16384  We[:,0:256]^T   [dd][o]
// total 589184 floats = ~2.36 MB

typedef short short8 __attribute__((ext_vector_type(8)));
typedef float f32x4 __attribute__((ext_vector_type(4)));

__device__ __forceinline__ unsigned short f2bf(float x) {
    unsigned u = __float_as_uint(x);
    return (unsigned short)((u + 0x7FFFu + ((u >> 16) & 1u)) >> 16);
}

// ---------------------------------------------------------------------------
// K1: projections + c1 + P. Blocks 0..47: 8 columns i each. Block 48: mask.
// Block 49: Wt. Blocks 50/51/52: WoT / WvE / WeN transposes (for coalesced
// weight reads in k_nf/k_edge).
__global__ __launch_bounds__(256) void k_proj(
    const float* __restrict__ nodes, const float* __restrict__ Wq,
    const float* __restrict__ Wk, const float* __restrict__ Wv,
    const float* __restrict__ Wo, const float* __restrict__ We,
    const unsigned int* __restrict__ mi, float* __restrict__ ws) {
    int tid = threadIdx.x;
    if (blockIdx.x >= 48) {
        if (blockIdx.x == 48) {
            __shared__ int bytemode;
            if (tid == 0) bytemode = 0;
            __syncthreads();
            unsigned v0 = mi[tid];
            unsigned v1 = (tid < 128) ? mi[256 + tid] : 0u;
            if (v0 > 1u || v1 > 1u) bytemode = 1;   // benign race
            __syncthreads();
            float* maskf = ws + WS_MASKF;
            for (int j = tid; j < NN; j += 256) {
                int on;
                if (bytemode) on = (((const unsigned char*)mi)[j] != 0);
                else          on = (mi[j] != 0u);
                maskf[j] = on ? 1.0f : 0.0f;
            }
        } else if (blockIdx.x == 49) {
            float* Wt = ws + WS_WT;
            for (int idx = tid; idx < 4096; idx += 256) {
                int c = idx >> 6, o = idx & 63;
                Wt[c * 64 + o] = We[o * 320 + 256 + c];
            }
        } else if (blockIdx.x == 50) {
            float* WoT = ws + WS_WOT;
            for (int idx = tid; idx < 32768; idx += 256) {
                int dd = idx >> 7, o = idx & 127;
                WoT[dd * 128 + o] = Wo[o * 256 + dd];
            }
        } else if (blockIdx.x == 51) {
            float* WvE = ws + WS_WVE;
            for (int idx = tid; idx < 16384; idx += 256) {
                int c = idx >> 8, d = idx & 255;
                WvE[c * 256 + d] = Wv[d * 192 + 128 + c];
            }
        } else {
            float* WeN = ws + WS_WEN;
            for (int idx = tid; idx < 16384; idx += 256) {
                int dd = idx >> 6, o = idx & 63;
                WeN[dd * 64 + o] = We[o * 320 + dd];
            }
        }
        return;
    }
    float* c1_ws = ws + WS_C1;
    float* P_ws  = ws + WS_P;
    float* vn_ws = ws + WS_VN;
    int i0 = blockIdx.x * 8;
    __shared__ float nl[128][8];
    __shared__ float q_l[256][8];
    __shared__ float qk_l[256][8];
    for (int idx = tid; idx < 1024; idx += 256) {
        int m = idx >> 3, ii = idx & 7;
        nl[m][ii] = nodes[m * NN + i0 + ii];
    }
    __syncthreads();
    int o = tid;
    float aq[8], ak[8], av[8];
#pragma unroll
    for (int ii = 0; ii < 8; ii++) { aq[ii] = 0.f; ak[ii] = 0.f; av[ii] = 0.f; }
#pragma unroll 4
    for (int m = 0; m < 128; m++) {
        float wq = Wq[o * 128 + m];
        float wk = Wk[o * 192 + m];
        float wv = Wv[o * 192 + m];
#pragma unroll
        for (int ii = 0; ii < 8; ii++) {
            float nv = nl[m][ii];
            aq[ii] = fmaf(wq, nv, aq[ii]);
            ak[ii] = fmaf(wk, nv, ak[ii]);
            av[ii] = fmaf(wv, nv, av[ii]);
        }
    }
#pragma unroll
    for (int ii = 0; ii < 8; ii++) {
        vn_ws[(size_t)(i0 + ii) * 256 + o] = av[ii];
        q_l[o][ii]  = aq[ii];
        qk_l[o][ii] = aq[ii] * ak[ii];
    }
    __syncthreads();
    if (tid < 64) {
        int h = tid >> 3, ii = tid & 7;
        float s = 0.f;
        for (int a = 0; a < 32; a++) s += qk_l[h * 32 + a][ii];
        c1_ws[(i0 + ii) * 8 + h] = s;
    }
    for (int rep = 0; rep < 2; rep++) {
        int idx = rep * 256 + tid;
        int c = idx & 63, h = idx >> 6;
        float ap[8];
#pragma unroll
        for (int ii = 0; ii < 8; ii++) ap[ii] = 0.f;
        for (int a = 0; a < 32; a++) {
            float w = Wk[(h * 32 + a) * 192 + 128 + c];
#pragma unroll
            for (int ii = 0; ii < 8; ii++)
                ap[ii] = fmaf(q_l[h * 32 + a][ii], w, ap[ii]);
        }
#pragma unroll
        for (int ii = 0; ii < 8; ii++)
            P_ws[(size_t)(i0 + ii) * 512 + c * 8 + h] = ap[ii];
    }
}

// ---------------------------------------------------------------------------
// K2: per-row attention. Block = one row i, 512 threads.
// pass1 (lanes=j): sim fp32 + e cached to LDS bf16, layout [c][392] (16B-
//   aligned rows -> MFMA B-fragments are contiguous b128 reads).
// softmax: read sim -> barrier -> overlay s as bf16 [h][392] over sT2.
// pass2: ONE wave, mfma_f32_16x16x32_bf16: T[16x64] = s[16x384]*e^T.
//   A-frag lane(m=L&15, k=quad*8+..): s rows (m>=8 aliased, D rows 8..15
//   discarded — row independence makes padding unnecessary).
//   Replaces the 8-wave scalar-LDS loop (was ~11.5K LDS-pipe cycles/block).
__global__ __launch_bounds__(512) void k_attn(
    const float* __restrict__ edges, const float* __restrict__ ws_ro,
    float* __restrict__ T_ws) {
    __shared__ __align__(16) unsigned short epad_h[64 * 392];  // 50176 B
    __shared__ __align__(16) float sT2[NN * 8];                // 12288 B
    const float* maskf = ws_ro + WS_MASKF;
    const float* c1w   = ws_ro + WS_C1;
    const float* Pw    = ws_ro + WS_P;
    int i = blockIdx.x;
    int tid = threadIdx.x;
    int wv = tid >> 6, ln = tid & 63;
    float mask_i = maskf[i];

    if (tid < NN) {
        int j = tid;
        const float* eb = edges + (size_t)i * NN + j;
        const float* Pi = Pw + (size_t)i * 512;
        float acc[8];
#pragma unroll
        for (int h = 0; h < 8; h++) acc[h] = 0.f;
#pragma unroll
        for (int cb = 0; cb < 4; cb++) {
            float ev[16];
#pragma unroll
            for (int t = 0; t < 16; t++)
                ev[t] = eb[(size_t)(cb * 16 + t) * NSQ];
#pragma unroll
            for (int t = 0; t < 16; t++) {
                int c = cb * 16 + t;
                epad_h[c * 392 + j] = f2bf(ev[t]);
                const float* Pc = Pi + c * 8;     // wave-uniform -> s_load
#pragma unroll
                for (int h = 0; h < 8; h++) acc[h] = fmaf(Pc[h], ev[t], acc[h]);
            }
        }
        float mj = maskf[j];
        const float* c1i = c1w + i * 8;
        float sv[8];
#pragma unroll
        for (int h = 0; h < 8; h++) {
            float s = (c1i[h] + acc[h]) * 0.17677669529663687f;
            sv[h] = (mj != 0.0f) ? s : -1e30f;
        }
        *reinterpret_cast<float4*>(&sT2[j * 8])     = make_float4(sv[0], sv[1], sv[2], sv[3]);
        *reinterpret_cast<float4*>(&sT2[j * 8 + 4]) = make_float4(sv[4], sv[5], sv[6], sv[7]);
    }
    __syncthreads();
    // softmax: wave wv owns head h=wv, lanes cover j = ln + 64k
    float v[6];
    {
        int h = wv;
#pragma unroll
        for (int k = 0; k < 6; k++) v[k] = sT2[(ln + 64 * k) * 8 + h];
    }
    __syncthreads();   // all sT2 reads done; safe to overlay s_bf below
    {
        int h = wv;
        float m = v[0];
#pragma unroll
        for (int k = 1; k < 6; k++) m = fmaxf(m, v[k]);
#pragma unroll
        for (int s = 1; s < 64; s <<= 1) m = fmaxf(m, __shfl_xor(m, s));
        float ex[6]; float sum = 0.f;
#pragma unroll
        for (int k = 0; k < 6; k++) { ex[k] = __expf(v[k] - m); sum += ex[k]; }
#pragma unroll
        for (int s = 1; s < 64; s <<= 1) sum += __shfl_xor(sum, s);
        float fac = mask_i / sum;
        unsigned short* s_bf = reinterpret_cast<unsigned short*>(sT2);
#pragma unroll
        for (int k = 0; k < 6; k++)
            s_bf[h * 392 + ln + 64 * k] = f2bf(ex[k] * fac);
    }
    __syncthreads();
    // pass2: single-wave MFMA chain
    if (tid < 64) {
        const unsigned short* s_bf = reinterpret_cast<const unsigned short*>(sT2);
        int L = tid;
        int nc   = L & 15;          // N index (c within tile) / A row m
        int quad = L >> 4;          // K sub-block
        int hrow = nc & 7;          // alias rows 8..15 -> 0..7 (D rows 8..15 dropped)
        f32x4 acc0 = {0.f, 0.f, 0.f, 0.f};
        f32x4 acc1 = {0.f, 0.f, 0.f, 0.f};
        f32x4 acc2 = {0.f, 0.f, 0.f, 0.f};
        f32x4 acc3 = {0.f, 0.f, 0.f, 0.f};
#pragma unroll
        for (int s = 0; s < 12; s++) {
            int jb = s * 32 + quad * 8;
            short8 a = *reinterpret_cast<const short8*>(&s_bf[hrow * 392 + jb]);
            short8 b0 = *reinterpret_cast<const short8*>(&epad_h[(0 * 16 + nc) * 392 + jb]);
            short8 b1 = *reinterpret_cast<const short8*>(&epad_h[(1 * 16 + nc) * 392 + jb]);
            short8 b2 = *reinterpret_cast<const short8*>(&epad_h[(2 * 16 + nc) * 392 + jb]);
            short8 b3 = *reinterpret_cast<const short8*>(&epad_h[(3 * 16 + nc) * 392 + jb]);
            acc0 = __builtin_amdgcn_mfma_f32_16x16x32_bf16(a, b0, acc0, 0, 0, 0);
            acc1 = __builtin_amdgcn_mfma_f32_16x16x32_bf16(a, b1, acc1, 0, 0, 0);
            acc2 = __builtin_amdgcn_mfma_f32_16x16x32_bf16(a, b2, acc2, 0, 0, 0);
            acc3 = __builtin_amdgcn_mfma_f32_16x16x32_bf16(a, b3, acc3, 0, 0, 0);
        }
        if (L < 32) {   // quads 0,1 hold D rows 0..7
            float* To = T_ws + (size_t)i * 512;
#pragma unroll
            for (int r = 0; r < 4; r++) {
                int h = quad * 4 + r;
                To[h * 64 +  0 + nc] = acc0[r];
                To[h * 64 + 16 + nc] = acc1[r];
                To[h * 64 + 32 + nc] = acc2[r];
                To[h * 64 + 48 + nc] = acc3[r];
            }
        }
    }
}

// ---------------------------------------------------------------------------
// K3: nf[d,i] = mask_i*vn + WvE^T@T ; node_out = Wo@nf ; g = 0.5*We[:,:256]@nf
// All weight reads via pre-transposed ws copies -> lane-contiguous.
__global__ __launch_bounds__(256) void k_nf(
    const float* __restrict__ ws_ro, float* __restrict__ gh_ws,
    float* __restrict__ out) {
    const float* maskf = ws_ro + WS_MASKF;
    const float* vn_ws = ws_ro + WS_VN;
    const float* T_ws  = ws_ro + WS_T;
    const float* WvE   = ws_ro + WS_WVE;
    const float* WoT   = ws_ro + WS_WOT;
    const float* WeN   = ws_ro + WS_WEN;
    int i = blockIdx.x, tid = threadIdx.x;
    __shared__ float T_l[512];
    __shared__ float nf_l[256];
    T_l[tid]       = T_ws[(size_t)i * 512 + tid];
    T_l[tid + 256] = T_ws[(size_t)i * 512 + 256 + tid];
    __syncthreads();
    int d = tid, h = d >> 5;
    float a0 = 0.f, a1 = 0.f, a2 = 0.f, a3 = 0.f;
#pragma unroll
    for (int c = 0; c < 64; c += 4) {
        a0 = fmaf(WvE[(c    ) * 256 + d], T_l[h * 64 + c    ], a0);
        a1 = fmaf(WvE[(c + 1) * 256 + d], T_l[h * 64 + c + 1], a1);
        a2 = fmaf(WvE[(c + 2) * 256 + d], T_l[h * 64 + c + 2], a2);
        a3 = fmaf(WvE[(c + 3) * 256 + d], T_l[h * 64 + c + 3], a3);
    }
    nf_l[d] = maskf[i] * vn_ws[(size_t)i * 256 + d] + ((a0 + a1) + (a2 + a3));
    __syncthreads();
    if (tid < 128) {
        int o = tid;
        float b0 = 0.f, b1 = 0.f, b2 = 0.f, b3 = 0.f;
#pragma unroll 8
        for (int dd = 0; dd < 256; dd += 4) {
            b0 = fmaf(WoT[(dd    ) * 128 + o], nf_l[dd    ], b0);
            b1 = fmaf(WoT[(dd + 1) * 128 + o], nf_l[dd + 1], b1);
            b2 = fmaf(WoT[(dd + 2) * 128 + o], nf_l[dd + 2], b2);
            b3 = fmaf(WoT[(dd + 3) * 128 + o], nf_l[dd + 3], b3);
        }
        out[o * NN + i] = (b0 + b1) + (b2 + b3);
    } else if (tid < 192) {
        int o = tid - 128;
        float b0 = 0.f, b1 = 0.f, b2 = 0.f, b3 = 0.f;
#pragma unroll 8
        for (int dd = 0; dd < 256; dd += 4) {
            b0 = fmaf(WeN[(dd    ) * 64 + o], nf_l[dd    ], b0);
            b1 = fmaf(WeN[(dd + 1) * 64 + o], nf_l[dd + 1], b1);
            b2 = fmaf(WeN[(dd + 2) * 64 + o], nf_l[dd + 2], b2);
            b3 = fmaf(WeN[(dd + 3) * 64 + o], nf_l[dd + 3], b3);
        }
        gh_ws[o * NN + i] = 0.5f * ((b0 + b1) + (b2 + b3));
    }
}

// ---------------------------------------------------------------------------
// K4: FINAL edge write: out_e[o,i,j] = gh[o,i]+gh[o,j]+sum_c Wt[c][o]*e[c,i,j]
// Block=(i, og of 16 o's); thread=j. ev[16] load batches for MLP; eo[16]
// accs only (spill trap avoided). Wt rows uniform -> s_load_dwordx16.
__global__ __launch_bounds__(384) void k_edge(
    const float* __restrict__ edges, const float* __restrict__ ws_ro,
    float* __restrict__ out_e) {
    const float* Wt = ws_ro + WS_WT;
    const float* gh = ws_ro + WS_GH;
    int i = blockIdx.x, og = blockIdx.y, j = threadIdx.x;
    float gj[16];
    const float* gb = gh + og * 16 * NN + j;
#pragma unroll
    for (int t = 0; t < 16; t++) gj[t] = gb[t * NN];
    float eo[16];
#pragma unroll
    for (int t = 0; t < 16; t++) eo[t] = 0.f;
    const float* eb = edges + (size_t)i * NN + j;
    const float* wtb = Wt + og * 16;
#pragma unroll
    for (int cb = 0; cb < 4; cb++) {
        float ev[16];
#pragma unroll
        for (int t = 0; t < 16; t++)
            ev[t] = eb[(size_t)(cb * 16 + t) * NSQ];
#pragma unroll
        for (int t = 0; t < 16; t++) {
            const float* wr = wtb + (cb * 16 + t) * 64;  // uniform -> s_load
#pragma unroll
            for (int u = 0; u < 16; u++) eo[u] = fmaf(wr[u], ev[t], eo[u]);
        }
    }
    size_t ob = (size_t)i * NN + j;
    const float* gib = gh + og * 16 * NN + i;
#pragma unroll
    for (int t = 0; t < 16; t++) {
        float gi = gib[t * NN];            // uniform -> s_load
        out_e[(size_t)(og * 16 + t) * NSQ + ob] = eo[t] + gi + gj[t];
    }
}

// ---------------------------------------------------------------------------
extern "C" void kernel_launch(void* const* d_in, const int* in_sizes, int n_in,
                              void* d_out, int out_size, void* d_ws, size_t ws_size,
                              hipStream_t stream) {
    const float* nodes = (const float*)d_in[0];
    const float* edges = (const float*)d_in[1];
    const unsigned int* mask = (const unsigned int*)d_in[2];
    const float* Wq = (const float*)d_in[3];
    const float* Wk = (const float*)d_in[4];
    const float* Wv = (const float*)d_in[5];
    const float* Wo = (const float*)d_in[6];
    const float* We = (const float*)d_in[7];
    float* out = (float*)d_out;
    float* ws  = (float*)d_ws;
    float* out_e = out + 128 * NN;

    hipLaunchKernelGGL(k_proj, dim3(53), dim3(256), 0, stream,
                       nodes, Wq, Wk, Wv, Wo, We, mask, ws);
    hipLaunchKernelGGL(k_attn, dim3(384), dim3(512), 0, stream,
                       edges, ws, ws + WS_T);
    hipLaunchKernelGGL(k_nf, dim3(384), dim3(256), 0, stream, ws,
                       ws + WS_GH, out);
    hipLaunchKernelGGL(k_edge, dim3(384, 4), dim3(384), 0, stream,
                       edges, ws, out_e);
}